// Round 1
// baseline (641.155 us; speedup 1.0000x reference)
//
#include <hip/hip_runtime.h>

#define NR    32768
#define NOBJ  16
#define NS    32
#define NB    64
#define WIDTH 576          // NB + NOBJ*NS
#define MISSV 1e10f

// ---- pinned fp32 ops: identical rounding in every kernel that shares the helper ----
__device__ __forceinline__ float fmulr(float a, float b){ return __fmul_rn(a,b); }
__device__ __forceinline__ float faddr(float a, float b){ return __fadd_rn(a,b); }
__device__ __forceinline__ float fsubr(float a, float b){ return __fsub_rn(a,b); }
__device__ __forceinline__ float fdvr (float a, float b){ return __fdiv_rn(a,b); }

struct RayObj {
  float oo[3];   // ray origin in object frame
  float dd[3];   // normalized ray dir in object frame
  float dw[3];   // normalized world dir
  float o[3];    // world origin
  float pm[9];   // world->object 3x3 (row-vector convention)
  float tm[3];   // translation row
  float t_in, dt;
  bool  hit;
};

// Shared by both kernels so hit/t_in/dt are bit-identical across them.
__device__ __forceinline__ void ray_obj_setup(
    const float* __restrict__ origins, const float* __restrict__ dirs,
    const float* __restrict__ trafos,  const float* __restrict__ scales,
    int m, int n, RayObj& R)
{
  const float o0 = origins[3*n+0], o1 = origins[3*n+1], o2 = origins[3*n+2];
  const float r0 = dirs[3*n+0],    r1 = dirs[3*n+1],    r2 = dirs[3*n+2];
  const float nn = __fsqrt_rn(faddr(faddr(fmulr(r0,r0), fmulr(r1,r1)), fmulr(r2,r2)));
  const float w0 = fdvr(r0,nn), w1 = fdvr(r1,nn), w2 = fdvr(r2,nn);

  const float* T = trafos + 16*m;
  const float* S = scales + 16*m;
  const float s0 = S[0], s1 = S[5], s2 = S[10];
  // pt_mat[:3,:3][i][j] = T[i][j]*s_j ; pt_mat[3,:3][j] = T[3][j]*s_j
  const float pm00 = fmulr(T[0],  s0), pm01 = fmulr(T[1],  s1), pm02 = fmulr(T[2],  s2);
  const float pm10 = fmulr(T[4],  s0), pm11 = fmulr(T[5],  s1), pm12 = fmulr(T[6],  s2);
  const float pm20 = fmulr(T[8],  s0), pm21 = fmulr(T[9],  s1), pm22 = fmulr(T[10], s2);
  const float tm0  = fmulr(T[12], s0), tm1  = fmulr(T[13], s1), tm2  = fmulr(T[14], s2);

  // origins_o[j] = sum_i o_i*pm[i][j] + tm[j]   (row-vector p @ M)
  const float oo0 = faddr(faddr(faddr(fmulr(o0,pm00), fmulr(o1,pm10)), fmulr(o2,pm20)), tm0);
  const float oo1 = faddr(faddr(faddr(fmulr(o0,pm01), fmulr(o1,pm11)), fmulr(o2,pm21)), tm1);
  const float oo2 = faddr(faddr(faddr(fmulr(o0,pm02), fmulr(o1,pm12)), fmulr(o2,pm22)), tm2);
  const float du0 = faddr(faddr(fmulr(w0,pm00), fmulr(w1,pm10)), fmulr(w2,pm20));
  const float du1 = faddr(faddr(fmulr(w0,pm01), fmulr(w1,pm11)), fmulr(w2,pm21));
  const float du2 = faddr(faddr(fmulr(w0,pm02), fmulr(w1,pm12)), fmulr(w2,pm22));
  const float dn  = __fsqrt_rn(faddr(faddr(fmulr(du0,du0), fmulr(du1,du1)), fmulr(du2,du2)));
  const float dd0 = fdvr(du0,dn), dd1 = fdvr(du1,dn), dd2 = fdvr(du2,dn);

  // slab vs unit cube
  const float i0 = fdvr(1.0f, dd0), i1 = fdvr(1.0f, dd1), i2 = fdvr(1.0f, dd2);
  const float a0 = fmulr(fsubr(-1.0f, oo0), i0), b0 = fmulr(fsubr(1.0f, oo0), i0);
  const float a1 = fmulr(fsubr(-1.0f, oo1), i1), b1 = fmulr(fsubr(1.0f, oo1), i1);
  const float a2 = fmulr(fsubr(-1.0f, oo2), i2), b2 = fmulr(fsubr(1.0f, oo2), i2);
  const float tmn = fmaxf(fmaxf(fminf(a0,b0), fminf(a1,b1)), fminf(a2,b2));
  const float tmx = fminf(fminf(fmaxf(a0,b0), fmaxf(a1,b1)), fmaxf(a2,b2));

  R.hit  = (tmx > tmn) && (tmx > 0.0f);
  R.t_in = fmaxf(tmn, 0.0f);
  R.dt   = fsubr(tmx, R.t_in);
  R.oo[0]=oo0; R.oo[1]=oo1; R.oo[2]=oo2;
  R.dd[0]=dd0; R.dd[1]=dd1; R.dd[2]=dd2;
  R.dw[0]=w0;  R.dw[1]=w1;  R.dw[2]=w2;
  R.o[0]=o0;   R.o[1]=o1;   R.o[2]=o2;
  R.pm[0]=pm00; R.pm[1]=pm01; R.pm[2]=pm02;
  R.pm[3]=pm10; R.pm[4]=pm11; R.pm[5]=pm12;
  R.pm[6]=pm20; R.pm[7]=pm21; R.pm[8]=pm22;
  R.tm[0]=tm0;  R.tm[1]=tm1;  R.tm[2]=tm2;
}

// ============ Kernel 1: pts_flat / dirs_flat (write-bound, coalesced float4) ============
__global__ __launch_bounds__(256) void k_ptsdirs(
    const float* __restrict__ origins, const float* __restrict__ dirs,
    const float* __restrict__ trafos,  const float* __restrict__ scales,
    float* __restrict__ outP, float* __restrict__ outD)
{
  __shared__ __align__(16) float ld[64][8];
  const int tid = threadIdx.x;
  const int m   = blockIdx.x >> 9;          // 16 objects
  const int n0  = (blockIdx.x & 511) << 6;  // 512 chunks of 64 rays
  if (tid < 64) {
    RayObj R;
    ray_obj_setup(origins, dirs, trafos, scales, m, n0 + tid, R);
    const bool h = R.hit;
    ld[tid][0] = h ? R.oo[0] : 0.0f;
    ld[tid][1] = h ? R.oo[1] : 0.0f;
    ld[tid][2] = h ? R.oo[2] : 0.0f;
    ld[tid][3] = h ? R.dd[0] : 0.0f;
    ld[tid][4] = h ? R.dd[1] : 0.0f;
    ld[tid][5] = h ? R.t_in  : 0.0f;
    ld[tid][6] = h ? R.dt    : 0.0f;
    ld[tid][7] = h ? R.dd[2] : 0.0f;
  }
  __syncthreads();
  // block region: 64 rays * 96 floats, contiguous. 1536 float4 per array.
  const size_t base = (size_t)(m * NR + n0) * 96;
  float4* P4 = (float4*)(outP + base);
  float4* D4 = (float4*)(outD + base);
  #pragma unroll
  for (int it = 0; it < 6; ++it) {
    const int f   = tid + (it << 8);   // float4 index, lane-consecutive -> coalesced
    const int rr  = f / 24;            // ray within block (24 float4 per ray)
    const int off = (f - rr * 24) * 4; // float offset within ray region [0,96)
    const float oox = ld[rr][0], ooy = ld[rr][1], ooz = ld[rr][2];
    const float ddx = ld[rr][3], ddy = ld[rr][4], ddz = ld[rr][7];
    const float ti  = ld[rr][5], dtt = ld[rr][6];
    float4 p, d;
    float* pp = (float*)&p; float* dv = (float*)&d;
    #pragma unroll
    for (int i = 0; i < 4; ++i) {
      const int idx = off + i;
      const int s   = idx / 3;
      const int c   = idx - s * 3;
      const float z  = ti + dtt * ((float)s * (1.0f/31.0f));
      const float oc = (c == 0) ? oox : ((c == 1) ? ooy : ooz);
      const float dc = (c == 0) ? ddx : ((c == 1) ? ddy : ddz);
      pp[i] = oc + dc * z;   // miss rays have all-zero params -> exact 0 output
      dv[i] = dc;
    }
    P4[f] = p;
    D4[f] = d;
  }
}

// count of elements in run m2 ordered before `key` (tie -> run m2 precedes)
__device__ __forceinline__ int count_run(const float* __restrict__ K,
                                         const float* __restrict__ A,
                                         const float* __restrict__ B,
                                         const float* __restrict__ IB,
                                         int m2, float key, bool tie)
{
  const float A2 = A[m2], B2 = B[m2];
  const float* V = K + NB + m2 * NS;
  if (B2 <= 0.0f) {  // degenerate run: all 32 keys equal A2
    return (A2 < key || (A2 == key && tie)) ? NS : 0;
  }
  float g = floorf(fmulr(fsubr(key, A2), IB[m2]));
  g = fminf(33.0f, fmaxf(-1.0f, g));
  int c = (int)g + 1;
  c = c < 0 ? 0 : (c > NS ? NS : c);
  // exact fixup against the actual stored keys (consistency => permutation)
  while (c > 0)  { const float v = V[c-1]; if (v < key || (v == key && tie)) break; --c; }
  while (c < NS) { const float v = V[c];   if (v < key || (v == key && tie)) ++c; else break; }
  return c;
}

// ============ Kernel 2: rank-based merge of 17 sorted runs, per-wave ray ============
__global__ __launch_bounds__(256) void k_sort(
    const float* __restrict__ origins, const float* __restrict__ dirs,
    const float* __restrict__ lengths,
    const float* __restrict__ trafos,  const float* __restrict__ scales,
    float* __restrict__ outL, float* __restrict__ outN, float* __restrict__ outM)
{
  __shared__ __align__(16) float sKeys[4][WIDTH];
  __shared__ __align__(16) float sA[4][NOBJ], sB[4][NOBJ], sIB[4][NOBJ];
  __shared__ __align__(16) float sL[4][WIDTH], sN[4][WIDTH], sM[4][WIDTH];

  const int tid  = threadIdx.x;
  const int wv   = tid >> 6;
  const int lane = tid & 63;
  const int n    = blockIdx.x * 4 + wv;

  // ---- phase A: lanes 0..15 compute per-object key-line params (fp64 for ordering fidelity)
  if (lane < NOBJ) {
    RayObj R;
    ray_obj_setup(origins, dirs, trafos, scales, lane, n, R);
    float myA = MISSV, myB = -1.0f, myIB = 0.0f;
    if (R.hit) {
      const double p00=R.pm[0], p01=R.pm[1], p02=R.pm[2];
      const double p10=R.pm[3], p11=R.pm[4], p12=R.pm[5];
      const double p20=R.pm[6], p21=R.pm[7], p22=R.pm[8];
      const double det = p00*(p11*p22-p12*p21) - p01*(p10*p22-p12*p20) + p02*(p10*p21-p11*p20);
      const double id  = 1.0/det;
      const double v00=(p11*p22-p12*p21)*id, v01=(p02*p21-p01*p22)*id, v02=(p01*p12-p02*p11)*id;
      const double v10=(p12*p20-p10*p22)*id, v11=(p00*p22-p02*p20)*id, v12=(p02*p10-p00*p12)*id;
      const double v20=(p10*p21-p11*p20)*id, v21=(p01*p20-p00*p21)*id, v22=(p00*p11-p01*p10)*id;
      const double q0=R.tm[0], q1=R.tm[1], q2=R.tm[2];
      const double ti0=-(q0*v00+q1*v10+q2*v20);
      const double ti1=-(q0*v01+q1*v11+q2*v21);
      const double ti2=-(q0*v02+q1*v12+q2*v22);
      const double e0=R.dd[0], e1=R.dd[1], e2=R.dd[2];
      const double g0=R.dw[0], g1=R.dw[1], g2=R.dw[2];
      const double u0=R.oo[0], u1=R.oo[1], u2=R.oo[2];
      const double dx = e0*v00+e1*v10+e2*v20;
      const double dy = e0*v01+e1*v11+e2*v21;
      const double dz = e0*v02+e1*v12+e2*v22;
      const double b  = dx*g0 + dy*g1 + dz*g2;                 // world z per object-space t
      const double ox = u0*v00+u1*v10+u2*v20 + ti0;
      const double oy = u0*v01+u1*v11+u2*v21 + ti1;
      const double oz = u0*v02+u1*v12+u2*v22 + ti2;
      const double a  = (ox-(double)R.o[0])*g0 + (oy-(double)R.o[1])*g1 + (oz-(double)R.o[2])*g2;
      const double Ad = a + b*(double)R.t_in;
      const double Bd = (b*(double)R.dt) * (1.0/31.0);
      myA = (float)Ad;
      myB = (float)Bd;
      if (!(myB >= 0.0f)) myB = 0.0f;              // safety: B>=0 by construction
      myIB = (myB > 0.0f) ? (1.0f/myB) : 0.0f;
    }
    sA[wv][lane]  = myA;
    sB[wv][lane]  = R.hit ? myB : -1.0f;           // B<0 encodes miss
    sIB[wv][lane] = myIB;
  }
  __syncthreads();

  // hit bitmask (wave-uniform; broadcast LDS reads)
  unsigned hm = 0;
  #pragma unroll
  for (int mm = 0; mm < NOBJ; ++mm) hm |= (sB[wv][mm] >= 0.0f ? 1u : 0u) << mm;
  const int H = __popc(hm);

  // ---- phase B: generate 576 keys (element e = lane + 64k)
  float kr[9];
  kr[0] = lengths[n * NB + lane];
  sKeys[wv][lane] = kr[0];
  #pragma unroll
  for (int k = 1; k < 9; ++k) {
    const int m0 = 2*(k-1) + (lane >> 5);
    const int s  = lane & 31;
    const float A_ = sA[wv][m0], B_ = sB[wv][m0];
    const float key = (B_ < 0.0f) ? MISSV : faddr(A_, fmulr(B_, (float)s));
    kr[k] = key;
    sKeys[wv][64*k + lane] = key;
  }
  __syncthreads();

  // ---- phase C: exact rank for each element, scatter triple into LDS
  const float* K = sKeys[wv];
  #pragma unroll
  for (int k = 0; k < 9; ++k) {
    const float key = kr[k];
    int rank; float nodef, maskf; float outkey = key;
    if (k == 0) {
      // base-length element e = lane; stable: precedes everything on ties
      rank = lane;
      unsigned mm = hm;
      while (mm) { const int m2 = __ffs(mm) - 1; mm &= mm - 1;
        rank += count_run(K, sA[wv], sB[wv], sIB[wv], m2, key, false); }
      nodef = -1.0f; maskf = 0.0f;
    } else {
      const int m = 2*(k-1) + (lane >> 5);
      const int s = lane & 31;
      if (!((hm >> m) & 1u)) {
        // miss element: closed-form tail rank (all non-miss keys < MISSV)
        const int MB = __popc((~hm) & ((1u << m) - 1u) & 0xFFFFu);
        rank  = NB + NS*H + NS*MB + s;
        nodef = -1.0f; maskf = 0.0f; outkey = MISSV;
      } else {
        rank = s;                                  // own run (strictly increasing)
        int c = 0;                                 // upper_bound over sorted lengths
        #pragma unroll
        for (int st = 64; st >= 1; st >>= 1) {
          const int t2 = c + st;
          if (t2 <= NB && K[t2-1] <= key) c = t2;
        }
        rank += c;
        unsigned mm = hm & ~(1u << m);
        while (mm) { const int m2 = __ffs(mm) - 1; mm &= mm - 1;
          rank += count_run(K, sA[wv], sB[wv], sIB[wv], m2, key, m2 < m); }
        nodef = (float)m; maskf = 1.0f;
      }
    }
    sL[wv][rank] = outkey;
    sN[wv][rank] = nodef;
    sM[wv][rank] = maskf;
  }
  __syncthreads();

  // ---- coalesced copy-out: 144 float4 per array per ray
  float4* pL = (float4*)(outL + (size_t)n * WIDTH);
  float4* pN = (float4*)(outN + (size_t)n * WIDTH);
  float4* pM = (float4*)(outM + (size_t)n * WIDTH);
  const float4* qL = (const float4*)sL[wv];
  const float4* qN = (const float4*)sN[wv];
  const float4* qM = (const float4*)sM[wv];
  for (int i = lane; i < WIDTH/4; i += 64) pL[i] = qL[i];
  for (int i = lane; i < WIDTH/4; i += 64) pN[i] = qN[i];
  for (int i = lane; i < WIDTH/4; i += 64) pM[i] = qM[i];
}

extern "C" void kernel_launch(void* const* d_in, const int* in_sizes, int n_in,
                              void* d_out, int out_size, void* d_ws, size_t ws_size,
                              hipStream_t stream)
{
  (void)in_sizes; (void)n_in; (void)out_size; (void)d_ws; (void)ws_size;
  const float* origins = (const float*)d_in[0];
  const float* dirs    = (const float*)d_in[1];
  const float* lengths = (const float*)d_in[2];
  const float* trafos  = (const float*)d_in[3];
  // d_in[4] = rots_w2o: its 3x3 equals trafos' 3x3 (dir transform) -> unused
  const float* scales  = (const float*)d_in[5];

  float* out  = (float*)d_out;
  float* outL = out;
  float* outN = out + (size_t)NR * WIDTH;
  float* outM = out + (size_t)2 * NR * WIDTH;
  float* outP = out + (size_t)3 * NR * WIDTH;
  float* outD = outP + (size_t)NOBJ * NR * NS * 3;

  hipLaunchKernelGGL(k_ptsdirs, dim3(NOBJ * 512), dim3(256), 0, stream,
                     origins, dirs, trafos, scales, outP, outD);
  hipLaunchKernelGGL(k_sort, dim3(NR / 4), dim3(256), 0, stream,
                     origins, dirs, lengths, trafos, scales, outL, outN, outM);
}

// Round 2
// 627.910 us; speedup vs baseline: 1.0211x; 1.0211x over previous
//
#include <hip/hip_runtime.h>

#define NR    32768
#define NOBJ  16
#define NS    32
#define NB    64
#define WIDTH 576          // NB + NOBJ*NS
#define MISSV 1e10f

// ---- pinned fp32 ops: identical rounding in every kernel that shares the helper ----
__device__ __forceinline__ float fmulr(float a, float b){ return __fmul_rn(a,b); }
__device__ __forceinline__ float faddr(float a, float b){ return __fadd_rn(a,b); }
__device__ __forceinline__ float fsubr(float a, float b){ return __fsub_rn(a,b); }
__device__ __forceinline__ float fdvr (float a, float b){ return __fdiv_rn(a,b); }

struct RayObj {
  float oo[3];   // ray origin in object frame
  float dd[3];   // normalized ray dir in object frame
  float t_in, dt;
  float dn;      // |d_w @ M3x3|  (object-t -> world-z divisor)
  bool  hit;
};

// Shared by both kernels so hit/t_in/dt are bit-identical across them.
__device__ __forceinline__ void ray_obj_setup(
    const float* __restrict__ origins, const float* __restrict__ dirs,
    const float* __restrict__ trafos,  const float* __restrict__ scales,
    int m, int n, RayObj& R)
{
  const float o0 = origins[3*n+0], o1 = origins[3*n+1], o2 = origins[3*n+2];
  const float r0 = dirs[3*n+0],    r1 = dirs[3*n+1],    r2 = dirs[3*n+2];
  const float nn = __fsqrt_rn(faddr(faddr(fmulr(r0,r0), fmulr(r1,r1)), fmulr(r2,r2)));
  const float w0 = fdvr(r0,nn), w1 = fdvr(r1,nn), w2 = fdvr(r2,nn);

  const float* T = trafos + 16*m;
  const float* S = scales + 16*m;
  const float s0 = S[0], s1 = S[5], s2 = S[10];
  // pt_mat[:3,:3][i][j] = T[i][j]*s_j ; pt_mat[3,:3][j] = T[3][j]*s_j
  const float pm00 = fmulr(T[0],  s0), pm01 = fmulr(T[1],  s1), pm02 = fmulr(T[2],  s2);
  const float pm10 = fmulr(T[4],  s0), pm11 = fmulr(T[5],  s1), pm12 = fmulr(T[6],  s2);
  const float pm20 = fmulr(T[8],  s0), pm21 = fmulr(T[9],  s1), pm22 = fmulr(T[10], s2);
  const float tm0  = fmulr(T[12], s0), tm1  = fmulr(T[13], s1), tm2  = fmulr(T[14], s2);

  // origins_o[j] = sum_i o_i*pm[i][j] + tm[j]   (row-vector p @ M)
  const float oo0 = faddr(faddr(faddr(fmulr(o0,pm00), fmulr(o1,pm10)), fmulr(o2,pm20)), tm0);
  const float oo1 = faddr(faddr(faddr(fmulr(o0,pm01), fmulr(o1,pm11)), fmulr(o2,pm21)), tm1);
  const float oo2 = faddr(faddr(faddr(fmulr(o0,pm02), fmulr(o1,pm12)), fmulr(o2,pm22)), tm2);
  const float du0 = faddr(faddr(fmulr(w0,pm00), fmulr(w1,pm10)), fmulr(w2,pm20));
  const float du1 = faddr(faddr(fmulr(w0,pm01), fmulr(w1,pm11)), fmulr(w2,pm21));
  const float du2 = faddr(faddr(fmulr(w0,pm02), fmulr(w1,pm12)), fmulr(w2,pm22));
  const float dn  = __fsqrt_rn(faddr(faddr(fmulr(du0,du0), fmulr(du1,du1)), fmulr(du2,du2)));
  const float dd0 = fdvr(du0,dn), dd1 = fdvr(du1,dn), dd2 = fdvr(du2,dn);

  // slab vs unit cube
  const float i0 = fdvr(1.0f, dd0), i1 = fdvr(1.0f, dd1), i2 = fdvr(1.0f, dd2);
  const float a0 = fmulr(fsubr(-1.0f, oo0), i0), b0 = fmulr(fsubr(1.0f, oo0), i0);
  const float a1 = fmulr(fsubr(-1.0f, oo1), i1), b1 = fmulr(fsubr(1.0f, oo1), i1);
  const float a2 = fmulr(fsubr(-1.0f, oo2), i2), b2 = fmulr(fsubr(1.0f, oo2), i2);
  const float tmn = fmaxf(fmaxf(fminf(a0,b0), fminf(a1,b1)), fminf(a2,b2));
  const float tmx = fminf(fminf(fmaxf(a0,b0), fmaxf(a1,b1)), fmaxf(a2,b2));

  R.hit  = (tmx > tmn) && (tmx > 0.0f);
  R.t_in = fmaxf(tmn, 0.0f);
  R.dt   = fsubr(tmx, R.t_in);
  R.dn   = dn;
  R.oo[0]=oo0; R.oo[1]=oo1; R.oo[2]=oo2;
  R.dd[0]=dd0; R.dd[1]=dd1; R.dd[2]=dd2;
}

// ============ Kernel 1: pts_flat / dirs_flat (write-bound, coalesced float4) ============
// UNCHANGED from round 1 (attribution experiment: only k_sort is modified this round).
__global__ __launch_bounds__(256) void k_ptsdirs(
    const float* __restrict__ origins, const float* __restrict__ dirs,
    const float* __restrict__ trafos,  const float* __restrict__ scales,
    float* __restrict__ outP, float* __restrict__ outD)
{
  __shared__ __align__(16) float ld[64][8];
  const int tid = threadIdx.x;
  const int m   = blockIdx.x >> 9;          // 16 objects
  const int n0  = (blockIdx.x & 511) << 6;  // 512 chunks of 64 rays
  if (tid < 64) {
    RayObj R;
    ray_obj_setup(origins, dirs, trafos, scales, m, n0 + tid, R);
    const bool h = R.hit;
    ld[tid][0] = h ? R.oo[0] : 0.0f;
    ld[tid][1] = h ? R.oo[1] : 0.0f;
    ld[tid][2] = h ? R.oo[2] : 0.0f;
    ld[tid][3] = h ? R.dd[0] : 0.0f;
    ld[tid][4] = h ? R.dd[1] : 0.0f;
    ld[tid][5] = h ? R.t_in  : 0.0f;
    ld[tid][6] = h ? R.dt    : 0.0f;
    ld[tid][7] = h ? R.dd[2] : 0.0f;
  }
  __syncthreads();
  // block region: 64 rays * 96 floats, contiguous. 1536 float4 per array.
  const size_t base = (size_t)(m * NR + n0) * 96;
  float4* P4 = (float4*)(outP + base);
  float4* D4 = (float4*)(outD + base);
  #pragma unroll
  for (int it = 0; it < 6; ++it) {
    const int f   = tid + (it << 8);   // float4 index, lane-consecutive -> coalesced
    const int rr  = f / 24;            // ray within block (24 float4 per ray)
    const int off = (f - rr * 24) * 4; // float offset within ray region [0,96)
    const float oox = ld[rr][0], ooy = ld[rr][1], ooz = ld[rr][2];
    const float ddx = ld[rr][3], ddy = ld[rr][4], ddz = ld[rr][7];
    const float ti  = ld[rr][5], dtt = ld[rr][6];
    float4 p, d;
    float* pp = (float*)&p; float* dv = (float*)&d;
    #pragma unroll
    for (int i = 0; i < 4; ++i) {
      const int idx = off + i;
      const int s   = idx / 3;
      const int c   = idx - s * 3;
      const float z  = ti + dtt * ((float)s * (1.0f/31.0f));
      const float oc = (c == 0) ? oox : ((c == 1) ? ooy : ooz);
      const float dc = (c == 0) ? ddx : ((c == 1) ? ddy : ddz);
      pp[i] = oc + dc * z;   // miss rays have all-zero params -> exact 0 output
      dv[i] = dc;
    }
    P4[f] = p;
    D4[f] = d;
  }
}

// count of elements in run m2 ordered before `key` (tie -> run m2 precedes)
__device__ __forceinline__ int count_run(const float* __restrict__ K,
                                         const float* __restrict__ A,
                                         const float* __restrict__ B,
                                         const float* __restrict__ IB,
                                         int m2, float key, bool tie)
{
  const float A2 = A[m2], B2 = B[m2];
  const float* V = K + NB + m2 * NS;
  if (B2 <= 0.0f) {  // degenerate run: all 32 keys equal A2
    return (A2 < key || (A2 == key && tie)) ? NS : 0;
  }
  float g = floorf(fmulr(fsubr(key, A2), IB[m2]));
  g = fminf(33.0f, fmaxf(-1.0f, g));
  int c = (int)g + 1;
  c = c < 0 ? 0 : (c > NS ? NS : c);
  // exact fixup against the actual stored keys (consistency => permutation)
  while (c > 0)  { const float v = V[c-1]; if (v < key || (v == key && tie)) break; --c; }
  while (c < NS) { const float v = V[c];   if (v < key || (v == key && tie)) ++c; else break; }
  return c;
}

// ============ Kernel 2: rank-based merge of 17 sorted runs, per-wave ray ============
// Round 2: closed-form A/B (z_w(s) = (t_in + dt*s/31)/dn) -- no 3x3 fp64 inverse,
// drastically lower VGPR pressure; sM plane dropped (mask == node >= 0) -> LDS 28.4 KB.
__global__ __launch_bounds__(256) void k_sort(
    const float* __restrict__ origins, const float* __restrict__ dirs,
    const float* __restrict__ lengths,
    const float* __restrict__ trafos,  const float* __restrict__ scales,
    float* __restrict__ outL, float* __restrict__ outN, float* __restrict__ outM)
{
  __shared__ __align__(16) float sKeys[4][WIDTH];
  __shared__ __align__(16) float sA[4][NOBJ], sB[4][NOBJ], sIB[4][NOBJ];
  __shared__ __align__(16) float sL[4][WIDTH], sN[4][WIDTH];

  const int tid  = threadIdx.x;
  const int wv   = tid >> 6;
  const int lane = tid & 63;
  const int n    = blockIdx.x * 4 + wv;

  // ---- phase A: lanes 0..15 compute per-object key-line params.
  // Exact-math identity: world z of object-t sample = t / dn  (dn = |d_w @ M3x3|),
  // because the object-space points lie on the world ray and the round-trip
  // through o2w collapses. One fp64 reciprocal replaces the 3x3 fp64 inverse.
  if (lane < NOBJ) {
    RayObj R;
    ray_obj_setup(origins, dirs, trafos, scales, lane, n, R);
    float myA = MISSV, myB = -1.0f, myIB = 0.0f;
    if (R.hit) {
      const double invdn = 1.0 / (double)R.dn;
      myA = (float)((double)R.t_in * invdn);
      myB = (float)(((double)R.dt * invdn) * (1.0 / 31.0));
      if (!(myB > 0.0f)) myB = 0.0f;               // safety: NaN/underflow -> degenerate run
      myIB = (myB > 0.0f) ? (1.0f / myB) : 0.0f;
    }
    sA[wv][lane]  = myA;
    sB[wv][lane]  = R.hit ? myB : -1.0f;           // B<0 encodes miss
    sIB[wv][lane] = myIB;
  }
  __syncthreads();

  // hit bitmask (wave-uniform; broadcast LDS reads)
  unsigned hm = 0;
  #pragma unroll
  for (int mm = 0; mm < NOBJ; ++mm) hm |= (sB[wv][mm] >= 0.0f ? 1u : 0u) << mm;
  const int H = __popc(hm);

  // ---- phase B: generate 576 keys (element e = lane + 64k)
  float kr[9];
  kr[0] = lengths[n * NB + lane];
  sKeys[wv][lane] = kr[0];
  #pragma unroll
  for (int k = 1; k < 9; ++k) {
    const int m0 = 2*(k-1) + (lane >> 5);
    const int s  = lane & 31;
    const float A_ = sA[wv][m0], B_ = sB[wv][m0];
    const float key = (B_ < 0.0f) ? MISSV : faddr(A_, fmulr(B_, (float)s));
    kr[k] = key;
    sKeys[wv][64*k + lane] = key;
  }
  __syncthreads();

  // ---- phase C: exact rank for each element, scatter (key,node) into LDS
  const float* K = sKeys[wv];
  #pragma unroll
  for (int k = 0; k < 9; ++k) {
    const float key = kr[k];
    int rank; float nodef; float outkey = key;
    if (k == 0) {
      // base-length element e = lane; stable: precedes everything on ties
      rank = lane;
      unsigned mm = hm;
      while (mm) { const int m2 = __ffs(mm) - 1; mm &= mm - 1;
        rank += count_run(K, sA[wv], sB[wv], sIB[wv], m2, key, false); }
      nodef = -1.0f;
    } else {
      const int m = 2*(k-1) + (lane >> 5);
      const int s = lane & 31;
      if (!((hm >> m) & 1u)) {
        // miss element: closed-form tail rank (all non-miss keys < MISSV)
        const int MB = __popc((~hm) & ((1u << m) - 1u) & 0xFFFFu);
        rank  = NB + NS*H + NS*MB + s;
        nodef = -1.0f; outkey = MISSV;
      } else {
        rank = s;                                  // own run (monotone, ties stable)
        int c = 0;                                 // upper_bound over sorted base lengths
        #pragma unroll
        for (int st = 64; st >= 1; st >>= 1) {
          const int t2 = c + st;
          if (t2 <= NB && K[t2-1] <= key) c = t2;
        }
        rank += c;
        unsigned mm = hm & ~(1u << m);
        while (mm) { const int m2 = __ffs(mm) - 1; mm &= mm - 1;
          rank += count_run(K, sA[wv], sB[wv], sIB[wv], m2, key, m2 < m); }
        nodef = (float)m;
      }
    }
    sL[wv][rank] = outkey;
    sN[wv][rank] = nodef;
  }
  __syncthreads();

  // ---- coalesced copy-out: 144 float4 per array per ray; mask derived from node
  float4* pL = (float4*)(outL + (size_t)n * WIDTH);
  float4* pN = (float4*)(outN + (size_t)n * WIDTH);
  float4* pM = (float4*)(outM + (size_t)n * WIDTH);
  const float4* qL = (const float4*)sL[wv];
  const float4* qN = (const float4*)sN[wv];
  for (int i = lane; i < WIDTH/4; i += 64) pL[i] = qL[i];
  for (int i = lane; i < WIDTH/4; i += 64) {
    const float4 nv = qN[i];
    float4 mv;
    mv.x = nv.x >= 0.0f ? 1.0f : 0.0f;
    mv.y = nv.y >= 0.0f ? 1.0f : 0.0f;
    mv.z = nv.z >= 0.0f ? 1.0f : 0.0f;
    mv.w = nv.w >= 0.0f ? 1.0f : 0.0f;
    pN[i] = nv;
    pM[i] = mv;
  }
}

extern "C" void kernel_launch(void* const* d_in, const int* in_sizes, int n_in,
                              void* d_out, int out_size, void* d_ws, size_t ws_size,
                              hipStream_t stream)
{
  (void)in_sizes; (void)n_in; (void)out_size; (void)d_ws; (void)ws_size;
  const float* origins = (const float*)d_in[0];
  const float* dirs    = (const float*)d_in[1];
  const float* lengths = (const float*)d_in[2];
  const float* trafos  = (const float*)d_in[3];
  // d_in[4] = rots_w2o: its 3x3 equals trafos' 3x3 (dir transform) -> unused
  const float* scales  = (const float*)d_in[5];

  float* out  = (float*)d_out;
  float* outL = out;
  float* outN = out + (size_t)NR * WIDTH;
  float* outM = out + (size_t)2 * NR * WIDTH;
  float* outP = out + (size_t)3 * NR * WIDTH;
  float* outD = outP + (size_t)NOBJ * NR * NS * 3;

  hipLaunchKernelGGL(k_ptsdirs, dim3(NOBJ * 512), dim3(256), 0, stream,
                     origins, dirs, trafos, scales, outP, outD);
  hipLaunchKernelGGL(k_sort, dim3(NR / 4), dim3(256), 0, stream,
                     origins, dirs, lengths, trafos, scales, outL, outN, outM);
}

// Round 3
// 623.311 us; speedup vs baseline: 1.0286x; 1.0074x over previous
//
#include <hip/hip_runtime.h>

#define NR    32768
#define NOBJ  16
#define NS    32
#define NB    64
#define WIDTH 576          // NB + NOBJ*NS
#define MISSV 1e10f

// ---- pinned fp32 ops: identical rounding everywhere ----
__device__ __forceinline__ float fmulr(float a, float b){ return __fmul_rn(a,b); }
__device__ __forceinline__ float faddr(float a, float b){ return __fadd_rn(a,b); }
__device__ __forceinline__ float fsubr(float a, float b){ return __fsub_rn(a,b); }
__device__ __forceinline__ float fdvr (float a, float b){ return __fdiv_rn(a,b); }

struct RayObj {
  float oo[3];   // ray origin in object frame
  float dd[3];   // normalized ray dir in object frame
  float t_in, dt;
  float dn;      // |d_w @ M3x3|  (object-t -> world-z divisor)
  bool  hit;
};

// Shared by both roles so hit/t_in/dt are bit-identical across them.
__device__ __forceinline__ void ray_obj_setup(
    const float* __restrict__ origins, const float* __restrict__ dirs,
    const float* __restrict__ trafos,  const float* __restrict__ scales,
    int m, int n, RayObj& R)
{
  const float o0 = origins[3*n+0], o1 = origins[3*n+1], o2 = origins[3*n+2];
  const float r0 = dirs[3*n+0],    r1 = dirs[3*n+1],    r2 = dirs[3*n+2];
  const float nn = __fsqrt_rn(faddr(faddr(fmulr(r0,r0), fmulr(r1,r1)), fmulr(r2,r2)));
  const float w0 = fdvr(r0,nn), w1 = fdvr(r1,nn), w2 = fdvr(r2,nn);

  const float* T = trafos + 16*m;
  const float* S = scales + 16*m;
  const float s0 = S[0], s1 = S[5], s2 = S[10];
  const float pm00 = fmulr(T[0],  s0), pm01 = fmulr(T[1],  s1), pm02 = fmulr(T[2],  s2);
  const float pm10 = fmulr(T[4],  s0), pm11 = fmulr(T[5],  s1), pm12 = fmulr(T[6],  s2);
  const float pm20 = fmulr(T[8],  s0), pm21 = fmulr(T[9],  s1), pm22 = fmulr(T[10], s2);
  const float tm0  = fmulr(T[12], s0), tm1  = fmulr(T[13], s1), tm2  = fmulr(T[14], s2);

  const float oo0 = faddr(faddr(faddr(fmulr(o0,pm00), fmulr(o1,pm10)), fmulr(o2,pm20)), tm0);
  const float oo1 = faddr(faddr(faddr(fmulr(o0,pm01), fmulr(o1,pm11)), fmulr(o2,pm21)), tm1);
  const float oo2 = faddr(faddr(faddr(fmulr(o0,pm02), fmulr(o1,pm12)), fmulr(o2,pm22)), tm2);
  const float du0 = faddr(faddr(fmulr(w0,pm00), fmulr(w1,pm10)), fmulr(w2,pm20));
  const float du1 = faddr(faddr(fmulr(w0,pm01), fmulr(w1,pm11)), fmulr(w2,pm21));
  const float du2 = faddr(faddr(fmulr(w0,pm02), fmulr(w1,pm12)), fmulr(w2,pm22));
  const float dn  = __fsqrt_rn(faddr(faddr(fmulr(du0,du0), fmulr(du1,du1)), fmulr(du2,du2)));
  const float dd0 = fdvr(du0,dn), dd1 = fdvr(du1,dn), dd2 = fdvr(du2,dn);

  const float i0 = fdvr(1.0f, dd0), i1 = fdvr(1.0f, dd1), i2 = fdvr(1.0f, dd2);
  const float a0 = fmulr(fsubr(-1.0f, oo0), i0), b0 = fmulr(fsubr(1.0f, oo0), i0);
  const float a1 = fmulr(fsubr(-1.0f, oo1), i1), b1 = fmulr(fsubr(1.0f, oo1), i1);
  const float a2 = fmulr(fsubr(-1.0f, oo2), i2), b2 = fmulr(fsubr(1.0f, oo2), i2);
  const float tmn = fmaxf(fmaxf(fminf(a0,b0), fminf(a1,b1)), fminf(a2,b2));
  const float tmx = fminf(fminf(fmaxf(a0,b0), fmaxf(a1,b1)), fmaxf(a2,b2));

  R.hit  = (tmx > tmn) && (tmx > 0.0f);
  R.t_in = fmaxf(tmn, 0.0f);
  R.dt   = fsubr(tmx, R.t_in);
  R.dn   = dn;
  R.oo[0]=oo0; R.oo[1]=oo1; R.oo[2]=oo2;
  R.dd[0]=dd0; R.dd[1]=dd1; R.dd[2]=dd2;
}

// count of elements in run m2 ordered before `key` (tie -> run m2 precedes)
__device__ __forceinline__ int count_run(const float* __restrict__ K,
                                         const float* __restrict__ A,
                                         const float* __restrict__ B,
                                         const float* __restrict__ IB,
                                         int m2, float key, bool tie)
{
  const float A2 = A[m2], B2 = B[m2];
  const float* V = K + NB + m2 * NS;
  if (B2 <= 0.0f) {  // degenerate run: all 32 keys equal A2
    return (A2 < key || (A2 == key && tie)) ? NS : 0;
  }
  float g = floorf(fmulr(fsubr(key, A2), IB[m2]));
  g = fminf(33.0f, fmaxf(-1.0f, g));
  int c = (int)g + 1;
  c = c < 0 ? 0 : (c > NS ? NS : c);
  while (c > 0)  { const float v = V[c-1]; if (v < key || (v == key && tie)) break; --c; }
  while (c < NS) { const float v = V[c];   if (v < key || (v == key && tie)) ++c; else break; }
  return c;
}

struct PtsS  { float ld[64][8]; };
struct SortS {
  float sKeys[4][WIDTH];
  float sA[4][NOBJ], sB[4][NOBJ], sIB[4][NOBJ];
  float sL[4][WIDTH], sN[4][WIDTH];
};
union __align__(16) Smem { PtsS p; SortS s; };

// ============ Fused kernel: even blocks write pts/dirs, odd blocks rank-sort ============
// Role interleave => every CU co-resides write-bound and VALU-bound blocks (m114 overlap).
__global__ __launch_bounds__(256) void k_fused(
    const float* __restrict__ origins, const float* __restrict__ dirs,
    const float* __restrict__ lengths,
    const float* __restrict__ trafos,  const float* __restrict__ scales,
    float* __restrict__ outL, float* __restrict__ outN, float* __restrict__ outM,
    float* __restrict__ outP, float* __restrict__ outD)
{
  __shared__ Smem U;
  const int tid  = threadIdx.x;
  const int role = blockIdx.x & 1;
  const int bid  = blockIdx.x >> 1;

  if (role == 0) {
    // ---------------- pts/dirs writer ----------------
    const int m   = bid >> 9;          // 16 objects
    const int n0  = (bid & 511) << 6;  // 512 chunks of 64 rays
    if (tid < 64) {
      RayObj R;
      ray_obj_setup(origins, dirs, trafos, scales, m, n0 + tid, R);
      const bool h = R.hit;
      U.p.ld[tid][0] = h ? R.oo[0] : 0.0f;
      U.p.ld[tid][1] = h ? R.oo[1] : 0.0f;
      U.p.ld[tid][2] = h ? R.oo[2] : 0.0f;
      U.p.ld[tid][3] = h ? R.dd[0] : 0.0f;
      U.p.ld[tid][4] = h ? R.dd[1] : 0.0f;
      U.p.ld[tid][5] = h ? R.t_in  : 0.0f;
      U.p.ld[tid][6] = h ? R.dt    : 0.0f;
      U.p.ld[tid][7] = h ? R.dd[2] : 0.0f;
    }
    __syncthreads();
    const size_t base = (size_t)(m * NR + n0) * 96;
    float4* P4 = (float4*)(outP + base);
    float4* D4 = (float4*)(outD + base);
    #pragma unroll
    for (int it = 0; it < 6; ++it) {
      const int f   = tid + (it << 8);   // float4 index, lane-consecutive -> coalesced
      const int rr  = f / 24;            // ray within block (24 float4 per ray)
      const int off = (f - rr * 24) * 4; // float offset within ray region [0,96)
      const float oox = U.p.ld[rr][0], ooy = U.p.ld[rr][1], ooz = U.p.ld[rr][2];
      const float ddx = U.p.ld[rr][3], ddy = U.p.ld[rr][4], ddz = U.p.ld[rr][7];
      const float ti  = U.p.ld[rr][5], dtt = U.p.ld[rr][6];
      float4 p, d;
      float* pp = (float*)&p; float* dv = (float*)&d;
      #pragma unroll
      for (int i = 0; i < 4; ++i) {
        const int idx = off + i;
        const int s   = idx / 3;
        const int c   = idx - s * 3;
        const float z  = ti + dtt * ((float)s * (1.0f/31.0f));
        const float oc = (c == 0) ? oox : ((c == 1) ? ooy : ooz);
        const float dc = (c == 0) ? ddx : ((c == 1) ? ddy : ddz);
        pp[i] = oc + dc * z;   // miss rays: all-zero params -> exact 0 output
        dv[i] = dc;
      }
      P4[f] = p;
      D4[f] = d;
    }
    return;
  }

  // ---------------- rank-sort (4 rays per block, one wave per ray) ----------------
  const int wv   = tid >> 6;
  const int lane = tid & 63;
  const int n    = bid * 4 + wv;

  // phase A: lanes 0..15 compute per-object key-line params.
  // Exact identity: world z of object-t sample = t/dn (round-trip through o2w collapses).
  if (lane < NOBJ) {
    RayObj R;
    ray_obj_setup(origins, dirs, trafos, scales, lane, n, R);
    float myA = MISSV, myB = -1.0f, myIB = 0.0f;
    if (R.hit) {
      const double invdn = 1.0 / (double)R.dn;
      myA = (float)((double)R.t_in * invdn);
      myB = (float)(((double)R.dt * invdn) * (1.0 / 31.0));
      if (!(myB > 0.0f)) myB = 0.0f;
      myIB = (myB > 0.0f) ? (1.0f / myB) : 0.0f;
    }
    U.s.sA[wv][lane]  = myA;
    U.s.sB[wv][lane]  = R.hit ? myB : -1.0f;       // B<0 encodes miss
    U.s.sIB[wv][lane] = myIB;
  }
  __syncthreads();

  unsigned hm = 0;
  #pragma unroll
  for (int mm = 0; mm < NOBJ; ++mm) hm |= (U.s.sB[wv][mm] >= 0.0f ? 1u : 0u) << mm;
  const int H = __popc(hm);

  // phase B: generate 576 keys (element e = lane + 64k)
  float kr[9];
  kr[0] = lengths[n * NB + lane];
  U.s.sKeys[wv][lane] = kr[0];
  #pragma unroll
  for (int k = 1; k < 9; ++k) {
    const int m0 = 2*(k-1) + (lane >> 5);
    const int s  = lane & 31;
    const float A_ = U.s.sA[wv][m0], B_ = U.s.sB[wv][m0];
    const float key = (B_ < 0.0f) ? MISSV : faddr(A_, fmulr(B_, (float)s));
    kr[k] = key;
    U.s.sKeys[wv][64*k + lane] = key;
  }
  __syncthreads();

  // phase C: exact rank per element, scatter (key,node) into LDS
  const float* K = U.s.sKeys[wv];
  #pragma unroll
  for (int k = 0; k < 9; ++k) {
    const float key = kr[k];
    int rank; float nodef; float outkey = key;
    if (k == 0) {
      rank = lane;                                 // stable: base precedes all on ties
      unsigned mm = hm;
      while (mm) { const int m2 = __ffs(mm) - 1; mm &= mm - 1;
        rank += count_run(K, U.s.sA[wv], U.s.sB[wv], U.s.sIB[wv], m2, key, false); }
      nodef = -1.0f;
    } else {
      const int m = 2*(k-1) + (lane >> 5);
      const int s = lane & 31;
      if (!((hm >> m) & 1u)) {
        const int MB = __popc((~hm) & ((1u << m) - 1u) & 0xFFFFu);
        rank  = NB + NS*H + NS*MB + s;             // closed-form tail rank
        nodef = -1.0f; outkey = MISSV;
      } else {
        rank = s;
        int c = 0;                                 // upper_bound over sorted base lengths
        #pragma unroll
        for (int st = 64; st >= 1; st >>= 1) {
          const int t2 = c + st;
          if (t2 <= NB && K[t2-1] <= key) c = t2;
        }
        rank += c;
        unsigned mm = hm & ~(1u << m);
        while (mm) { const int m2 = __ffs(mm) - 1; mm &= mm - 1;
          rank += count_run(K, U.s.sA[wv], U.s.sB[wv], U.s.sIB[wv], m2, key, m2 < m); }
        nodef = (float)m;
      }
    }
    U.s.sL[wv][rank] = outkey;
    U.s.sN[wv][rank] = nodef;
  }
  __syncthreads();

  // coalesced copy-out: 144 float4 per array per ray; mask derived from node
  float4* pL = (float4*)(outL + (size_t)n * WIDTH);
  float4* pN = (float4*)(outN + (size_t)n * WIDTH);
  float4* pM = (float4*)(outM + (size_t)n * WIDTH);
  const float4* qL = (const float4*)U.s.sL[wv];
  const float4* qN = (const float4*)U.s.sN[wv];
  for (int i = lane; i < WIDTH/4; i += 64) pL[i] = qL[i];
  for (int i = lane; i < WIDTH/4; i += 64) {
    const float4 nv = qN[i];
    float4 mv;
    mv.x = nv.x >= 0.0f ? 1.0f : 0.0f;
    mv.y = nv.y >= 0.0f ? 1.0f : 0.0f;
    mv.z = nv.z >= 0.0f ? 1.0f : 0.0f;
    mv.w = nv.w >= 0.0f ? 1.0f : 0.0f;
    pN[i] = nv;
    pM[i] = mv;
  }
}

extern "C" void kernel_launch(void* const* d_in, const int* in_sizes, int n_in,
                              void* d_out, int out_size, void* d_ws, size_t ws_size,
                              hipStream_t stream)
{
  (void)in_sizes; (void)n_in; (void)out_size; (void)d_ws; (void)ws_size;
  const float* origins = (const float*)d_in[0];
  const float* dirs    = (const float*)d_in[1];
  const float* lengths = (const float*)d_in[2];
  const float* trafos  = (const float*)d_in[3];
  // d_in[4] = rots_w2o: its 3x3 equals trafos' 3x3 (dir transform) -> unused
  const float* scales  = (const float*)d_in[5];

  float* out  = (float*)d_out;
  float* outL = out;
  float* outN = out + (size_t)NR * WIDTH;
  float* outM = out + (size_t)2 * NR * WIDTH;
  float* outP = out + (size_t)3 * NR * WIDTH;
  float* outD = outP + (size_t)NOBJ * NR * NS * 3;

  // even blocks: 8192 pts-writer tiles; odd blocks: 8192 sort blocks (4 rays each)
  hipLaunchKernelGGL(k_fused, dim3(16384), dim3(256), 0, stream,
                     origins, dirs, lengths, trafos, scales,
                     outL, outN, outM, outP, outD);
}